// Round 13
// baseline (212.857 us; speedup 1.0000x reference)
//
#include <hip/hip_runtime.h>
#include <math.h>

#define D 256
#define NH 8
#define NL 4
#define NP 4
#define DFF 2048
#define HD 32
#define BB 2
#define LEN 5440
#define MROWS (BB * LEN)   // 10880 = 85*128 = 340*32

typedef __attribute__((ext_vector_type(8))) short short8;
typedef __attribute__((ext_vector_type(4))) float f32x4;
typedef unsigned int uint32;

__device__ __forceinline__ unsigned short f2bf(float f) {
    uint32 u = __float_as_uint(f);
    u += 0x7FFF + ((u >> 16) & 1);           // round-to-nearest-even
    return (unsigned short)(u >> 16);
}
__device__ __forceinline__ float bf2f(unsigned short h) {
    return __uint_as_float(((uint32)h) << 16);
}
__device__ __forceinline__ uint32 pack2(float a, float b) {
    return (uint32)f2bf(a) | ((uint32)f2bf(b) << 16);
}

// XCD-affinity swizzle: 85 row-tiles x ncols col-tiles.
__device__ __forceinline__ void swz85(int b, int ncols, int& row, int& col) {
    const int gsz = ncols << 3;
    const int full = 10 * gsz;
    if (b < full) {
        const int g = b / gsz, idx = b - g * gsz;
        row = (g << 3) + (idx & 7);
        col = idx >> 3;
    } else {
        const int idx = b - full;
        row = 80 + idx % 5;
        col = idx / 5;
    }
}

// ---------------------------------------------------------------------------
// prep: all weight transposes (fp32 [KxN] -> bf16 [NxK]) + bias concat.
// ---------------------------------------------------------------------------
__global__ void prep(const float* __restrict__ w_value, const float* __restrict__ w_off,
                     const float* __restrict__ w_attn, const float* __restrict__ w_out,
                     const float* __restrict__ w1, const float* __restrict__ w2,
                     const float* __restrict__ b_value, const float* __restrict__ b_off,
                     const float* __restrict__ b_attn,
                     unsigned short* __restrict__ wqvT, unsigned short* __restrict__ woT,
                     unsigned short* __restrict__ w1T, unsigned short* __restrict__ w2T,
                     float* __restrict__ bqv) {
    const int blk = blockIdx.x;
    if (blk >= 1248) {
        for (int i = threadIdx.x; i < 640; i += 256)
            bqv[i] = (i < 256) ? b_value[i] : (i < 512 ? b_off[i - 256] : b_attn[i - 512]);
        return;
    }
    const float* W; unsigned short* WT; int K, N, tid;
    if (blk < 64)       { W = w_value; WT = wqvT;             K = 256;  N = 256;  tid = blk; }
    else if (blk < 128) { W = w_off;   WT = wqvT + 256 * 256; K = 256;  N = 256;  tid = blk - 64; }
    else if (blk < 160) { W = w_attn;  WT = wqvT + 512 * 256; K = 256;  N = 128;  tid = blk - 128; }
    else if (blk < 224) { W = w_out;   WT = woT;              K = 256;  N = 256;  tid = blk - 160; }
    else if (blk < 736) { W = w1;      WT = w1T;              K = 256;  N = 2048; tid = blk - 224; }
    else                { W = w2;      WT = w2T;              K = 2048; N = 256;  tid = blk - 736; }
    const int ntx = N >> 5;
    const int nb = (tid % ntx) * 32, kb = (tid / ntx) * 32;

    __shared__ float tile[32][33];
    const int tx = threadIdx.x & 31, ty = threadIdx.x >> 5;
#pragma unroll
    for (int i = 0; i < 32; i += 8)
        tile[ty + i][tx] = W[(size_t)(kb + ty + i) * N + nb + tx];
    __syncthreads();
#pragma unroll
    for (int i = 0; i < 32; i += 8)
        WT[(size_t)(nb + ty + i) * K + kb + tx] = f2bf(tile[tx][ty + i]);
}

// ---------------------------------------------------------------------------
// ffn1 GEMM: C = relu(A @ BT^T + bias) -> bf16. 128x128 tile, pipelined.
// ---------------------------------------------------------------------------
__global__ __launch_bounds__(256) void ffn1_gemm(
        const unsigned short* __restrict__ A,
        const unsigned short* __restrict__ BT, const float* __restrict__ bias,
        unsigned short* __restrict__ Cv, int N, int K, int lda, int ldb) {
    __shared__ unsigned short Ash[128][40];
    __shared__ unsigned short Bsh[128][40];

    int rowt, colt;
    swz85(blockIdx.x, N >> 7, rowt, colt);
    const int row0 = rowt * 128, col0 = colt * 128;

    const int t = threadIdx.x;
    const int wave = t >> 6, lane = t & 63;
    const int wr = wave >> 1, wc = wave & 1;
    const int lrow = lane & 15, quad = lane >> 4;
    const int srow = t >> 1;
    const int cb = (t & 1) * 16;

    const unsigned short* ap = A + (size_t)(row0 + srow) * lda + cb;
    const unsigned short* bp = BT + (size_t)(col0 + srow) * ldb + cb;

    f32x4 acc[4][4];
#pragma unroll
    for (int i = 0; i < 4; i++)
#pragma unroll
        for (int j = 0; j < 4; j++) acc[i][j] = (f32x4){0.f, 0.f, 0.f, 0.f};

    uint4 ra0 = *(const uint4*)(ap + 0), ra1 = *(const uint4*)(ap + 8);
    uint4 rb0 = *(const uint4*)(bp + 0), rb1 = *(const uint4*)(bp + 8);

    for (int kb = 0; kb < K; kb += 32) {
        __syncthreads();
        *(uint4*)&Ash[srow][cb + 0] = ra0;
        *(uint4*)&Ash[srow][cb + 8] = ra1;
        *(uint4*)&Bsh[srow][cb + 0] = rb0;
        *(uint4*)&Bsh[srow][cb + 8] = rb1;
        __syncthreads();
        if (kb + 32 < K) {
            ra0 = *(const uint4*)(ap + kb + 32 + 0);
            ra1 = *(const uint4*)(ap + kb + 32 + 8);
            rb0 = *(const uint4*)(bp + kb + 32 + 0);
            rb1 = *(const uint4*)(bp + kb + 32 + 8);
        }

        short8 af[4], bfr[4];
#pragma unroll
        for (int mt = 0; mt < 4; mt++)
            af[mt] = *(const short8*)&Ash[wr * 64 + mt * 16 + lrow][quad * 8];
#pragma unroll
        for (int nt = 0; nt < 4; nt++)
            bfr[nt] = *(const short8*)&Bsh[wc * 64 + nt * 16 + lrow][quad * 8];
#pragma unroll
        for (int mt = 0; mt < 4; mt++)
#pragma unroll
            for (int nt = 0; nt < 4; nt++)
                acc[mt][nt] = __builtin_amdgcn_mfma_f32_16x16x32_bf16(
                    af[mt], bfr[nt], acc[mt][nt], 0, 0, 0);
    }

#pragma unroll
    for (int nt = 0; nt < 4; nt++) {
        const int col = col0 + wc * 64 + nt * 16 + lrow;
        const float bv = bias[col];
#pragma unroll
        for (int mt = 0; mt < 4; mt++) {
            f32x4 a = acc[mt][nt];
#pragma unroll
            for (int r = 0; r < 4; r++) {
                const int row = row0 + wr * 64 + mt * 16 + quad * 4 + r;
                Cv[(size_t)row * N + col] = f2bf(fmaxf(a[r] + bv, 0.f));
            }
        }
    }
}

// ---------------------------------------------------------------------------
// Split-K GEMM (N=256): flat grid 85 x (2 cols x NZ kchunks), swizzled.
// partial[z] = A[:, z*KC:] @ BT[:, z*KC:]^T, stored BF16 (halves traffic;
// each partial O(1) so rounding adds <~0.02 pre-LN worst case).
// ---------------------------------------------------------------------------
template <int NZ>
__global__ __launch_bounds__(256) void splitk_gemm(
        const unsigned short* __restrict__ A, const unsigned short* __restrict__ BT,
        unsigned short* __restrict__ part, int KC, int lda, int ldb) {
    __shared__ unsigned short Ash[128][40];
    __shared__ unsigned short Bsh[128][40];

    int rowt, cc;
    swz85(blockIdx.x, 2 * NZ, rowt, cc);
    const int row0 = rowt * 128;
    const int col0 = (cc & 1) * 128;
    const int z = cc >> 1;
    const int koff = z * KC;
    unsigned short* __restrict__ C = part + (size_t)z * MROWS * 256;

    const int t = threadIdx.x;
    const int wave = t >> 6, lane = t & 63;
    const int wr = wave >> 1, wc = wave & 1;
    const int lrow = lane & 15, quad = lane >> 4;
    const int srow = t >> 1;
    const int cb = (t & 1) * 16;

    const unsigned short* ap = A + (size_t)(row0 + srow) * lda + koff + cb;
    const unsigned short* bp = BT + (size_t)(col0 + srow) * ldb + koff + cb;

    f32x4 acc[4][4];
#pragma unroll
    for (int i = 0; i < 4; i++)
#pragma unroll
        for (int j = 0; j < 4; j++) acc[i][j] = (f32x4){0.f, 0.f, 0.f, 0.f};

    uint4 ra0 = *(const uint4*)(ap + 0), ra1 = *(const uint4*)(ap + 8);
    uint4 rb0 = *(const uint4*)(bp + 0), rb1 = *(const uint4*)(bp + 8);

    for (int kb = 0; kb < KC; kb += 32) {
        __syncthreads();
        *(uint4*)&Ash[srow][cb + 0] = ra0;
        *(uint4*)&Ash[srow][cb + 8] = ra1;
        *(uint4*)&Bsh[srow][cb + 0] = rb0;
        *(uint4*)&Bsh[srow][cb + 8] = rb1;
        __syncthreads();
        if (kb + 32 < KC) {
            ra0 = *(const uint4*)(ap + kb + 32 + 0);
            ra1 = *(const uint4*)(ap + kb + 32 + 8);
            rb0 = *(const uint4*)(bp + kb + 32 + 0);
            rb1 = *(const uint4*)(bp + kb + 32 + 8);
        }

        short8 af[4], bfr[4];
#pragma unroll
        for (int mt = 0; mt < 4; mt++)
            af[mt] = *(const short8*)&Ash[wr * 64 + mt * 16 + lrow][quad * 8];
#pragma unroll
        for (int nt = 0; nt < 4; nt++)
            bfr[nt] = *(const short8*)&Bsh[wc * 64 + nt * 16 + lrow][quad * 8];
#pragma unroll
        for (int mt = 0; mt < 4; mt++)
#pragma unroll
            for (int nt = 0; nt < 4; nt++)
                acc[mt][nt] = __builtin_amdgcn_mfma_f32_16x16x32_bf16(
                    af[mt], bfr[nt], acc[mt][nt], 0, 0, 0);
    }

#pragma unroll
    for (int nt = 0; nt < 4; nt++) {
        const int col = col0 + wc * 64 + nt * 16 + lrow;
#pragma unroll
        for (int mt = 0; mt < 4; mt++) {
            f32x4 a = acc[mt][nt];
#pragma unroll
            for (int r = 0; r < 4; r++) {
                const int row = row0 + wr * 64 + mt * 16 + quad * 4 + r;
                C[(size_t)row * 256 + col] = f2bf(a[r]);
            }
        }
    }
}

// ---------------------------------------------------------------------------
// Fused GEMM + bias + residual + LayerNorm (K=256 proj only — 8 K-iters,
// barrier cost acceptable; NOT for K=2048: measured 49us there, barrier-bound).
// Tile 32 rows x 256 cols, full K. Grid = M/32 = 340.
// ---------------------------------------------------------------------------
template <bool WRITE16>
__global__ __launch_bounds__(256) void gemm_ln(
        const unsigned short* __restrict__ A, const unsigned short* __restrict__ BT,
        const float* __restrict__ bias, const float* __restrict__ rsd,
        const float* __restrict__ g, const float* __restrict__ be,
        float* __restrict__ out, unsigned short* __restrict__ out16, int K) {
    __shared__ __align__(16) unsigned short Ash[32][40];
    __shared__ __align__(16) unsigned short Bsh[256][40];
    __shared__ float red1[4][32], red2[4][32];

    const int row0 = blockIdx.x * 32;
    const int t = threadIdx.x;
    const int wave = t >> 6, lane = t & 63;
    const int lrow = lane & 15, quad = lane >> 4;

    const int ar = t >> 3, ac = (t & 7) * 4;
    const unsigned short* ap = A + (size_t)(row0 + ar) * K + ac;
    const int br = t >> 1, cb = (t & 1) * 16;
    const unsigned short* bp0 = BT + (size_t)br * K + cb;
    const unsigned short* bp1 = BT + (size_t)(128 + br) * K + cb;

    f32x4 acc[2][4];
#pragma unroll
    for (int i = 0; i < 2; i++)
#pragma unroll
        for (int j = 0; j < 4; j++) acc[i][j] = (f32x4){0.f, 0.f, 0.f, 0.f};

    uint2 ra = *(const uint2*)ap;
    uint4 rb00 = *(const uint4*)(bp0 + 0), rb01 = *(const uint4*)(bp0 + 8);
    uint4 rb10 = *(const uint4*)(bp1 + 0), rb11 = *(const uint4*)(bp1 + 8);

    for (int kb = 0; kb < K; kb += 32) {
        __syncthreads();
        *(uint2*)&Ash[ar][ac] = ra;
        *(uint4*)&Bsh[br][cb + 0] = rb00;
        *(uint4*)&Bsh[br][cb + 8] = rb01;
        *(uint4*)&Bsh[128 + br][cb + 0] = rb10;
        *(uint4*)&Bsh[128 + br][cb + 8] = rb11;
        __syncthreads();
        if (kb + 32 < K) {
            ra   = *(const uint2*)(ap + kb + 32);
            rb00 = *(const uint4*)(bp0 + kb + 32 + 0);
            rb01 = *(const uint4*)(bp0 + kb + 32 + 8);
            rb10 = *(const uint4*)(bp1 + kb + 32 + 0);
            rb11 = *(const uint4*)(bp1 + kb + 32 + 8);
        }

        short8 af[2], bfr[4];
#pragma unroll
        for (int mt = 0; mt < 2; mt++)
            af[mt] = *(const short8*)&Ash[mt * 16 + lrow][quad * 8];
#pragma unroll
        for (int nt = 0; nt < 4; nt++)
            bfr[nt] = *(const short8*)&Bsh[wave * 64 + nt * 16 + lrow][quad * 8];
#pragma unroll
        for (int mt = 0; mt < 2; mt++)
#pragma unroll
            for (int nt = 0; nt < 4; nt++)
                acc[mt][nt] = __builtin_amdgcn_mfma_f32_16x16x32_bf16(
                    af[mt], bfr[nt], acc[mt][nt], 0, 0, 0);
    }

    float gv[4], bev[4], bv[4];
#pragma unroll
    for (int nt = 0; nt < 4; nt++) {
        const int col = wave * 64 + nt * 16 + lrow;
        bv[nt] = bias[col];
        gv[nt] = g[col];
        bev[nt] = be[col];
    }

    float v[2][4][4];
#pragma unroll
    for (int mt = 0; mt < 2; mt++)
#pragma unroll
        for (int r = 0; r < 4; r++) {
            const int row = row0 + mt * 16 + quad * 4 + r;
#pragma unroll
            for (int nt = 0; nt < 4; nt++) {
                const int col = wave * 64 + nt * 16 + lrow;
                v[mt][nt][r] = acc[mt][nt][r] + bv[nt] + rsd[(size_t)row * 256 + col];
            }
        }

#pragma unroll
    for (int mt = 0; mt < 2; mt++)
#pragma unroll
        for (int r = 0; r < 4; r++) {
            float s1 = v[mt][0][r] + v[mt][1][r] + v[mt][2][r] + v[mt][3][r];
            float s2 = v[mt][0][r] * v[mt][0][r] + v[mt][1][r] * v[mt][1][r] +
                       v[mt][2][r] * v[mt][2][r] + v[mt][3][r] * v[mt][3][r];
#pragma unroll
            for (int o = 1; o < 16; o <<= 1) {
                s1 += __shfl_xor(s1, o, 16);
                s2 += __shfl_xor(s2, o, 16);
            }
            if (lrow == 0) {
                const int rr = mt * 16 + quad * 4 + r;
                red1[wave][rr] = s1;
                red2[wave][rr] = s2;
            }
        }
    __syncthreads();

#pragma unroll
    for (int mt = 0; mt < 2; mt++)
#pragma unroll
        for (int r = 0; r < 4; r++) {
            const int rr = mt * 16 + quad * 4 + r;
            const float su = red1[0][rr] + red1[1][rr] + red1[2][rr] + red1[3][rr];
            const float sq = red2[0][rr] + red2[1][rr] + red2[2][rr] + red2[3][rr];
            const float mean = su * (1.0f / 256.0f);
            const float var = fmaxf(sq * (1.0f / 256.0f) - mean * mean, 0.f);
            const float rstd = rsqrtf(var + 1e-5f);
            const size_t rowoff = (size_t)(row0 + rr) * 256;
#pragma unroll
            for (int nt = 0; nt < 4; nt++) {
                const int col = wave * 64 + nt * 16 + lrow;
                const float o = (v[mt][nt][r] - mean) * rstd * gv[nt] + bev[nt];
                out[rowoff + col] = o;
                if (WRITE16) out16[rowoff + col] = f2bf(o);
            }
        }
}

// ---------------------------------------------------------------------------
// Merged value+query GEMM: flat grid 425 = 85 rows x 5 cols, swizzled.
// ---------------------------------------------------------------------------
__global__ __launch_bounds__(256) void qv_gemm(
        const float* __restrict__ src, const float* __restrict__ pos,
        const unsigned short* __restrict__ BT, const float* __restrict__ bias,
        unsigned short* __restrict__ val, float* __restrict__ qout) {
    __shared__ unsigned short Ash[128][40];
    __shared__ unsigned short Bsh[128][40];

    int rowt, colt;
    swz85(blockIdx.x, 5, rowt, colt);
    const int row0 = rowt * 128, col0 = colt * 128;
    const bool addp = (col0 >= 256);

    const int t = threadIdx.x;
    const int wave = t >> 6, lane = t & 63;
    const int wr = wave >> 1, wc = wave & 1;
    const int lrow = lane & 15, quad = lane >> 4;
    const int srow = t >> 1;
    const int cb = (t & 1) * 16;

    const float* ap = src + (size_t)(row0 + srow) * 256 + cb;
    const float* pp = pos + (size_t)(row0 + srow) * 256 + cb;
    const unsigned short* bp = BT + (size_t)(col0 + srow) * 256 + cb;

    f32x4 acc[4][4];
#pragma unroll
    for (int i = 0; i < 4; i++)
#pragma unroll
        for (int j = 0; j < 4; j++) acc[i][j] = (f32x4){0.f, 0.f, 0.f, 0.f};

    float4 fa[4]; float4 fp[4]; uint4 rb0, rb1;
#pragma unroll
    for (int j = 0; j < 4; j++) fa[j] = *(const float4*)(ap + 4 * j);
    if (addp) {
#pragma unroll
        for (int j = 0; j < 4; j++) fp[j] = *(const float4*)(pp + 4 * j);
    }
    rb0 = *(const uint4*)(bp + 0);
    rb1 = *(const uint4*)(bp + 8);

    for (int kb = 0; kb < 256; kb += 32) {
        __syncthreads();
        {
            float4 f0 = fa[0], f1 = fa[1], f2 = fa[2], f3 = fa[3];
            if (addp) {
                f0.x += fp[0].x; f0.y += fp[0].y; f0.z += fp[0].z; f0.w += fp[0].w;
                f1.x += fp[1].x; f1.y += fp[1].y; f1.z += fp[1].z; f1.w += fp[1].w;
                f2.x += fp[2].x; f2.y += fp[2].y; f2.z += fp[2].z; f2.w += fp[2].w;
                f3.x += fp[3].x; f3.y += fp[3].y; f3.z += fp[3].z; f3.w += fp[3].w;
            }
            uint4 u0 = make_uint4(pack2(f0.x, f0.y), pack2(f0.z, f0.w),
                                  pack2(f1.x, f1.y), pack2(f1.z, f1.w));
            uint4 u1 = make_uint4(pack2(f2.x, f2.y), pack2(f2.z, f2.w),
                                  pack2(f3.x, f3.y), pack2(f3.z, f3.w));
            *(uint4*)&Ash[srow][cb + 0] = u0;
            *(uint4*)&Ash[srow][cb + 8] = u1;
            *(uint4*)&Bsh[srow][cb + 0] = rb0;
            *(uint4*)&Bsh[srow][cb + 8] = rb1;
        }
        __syncthreads();
        if (kb + 32 < 256) {
#pragma unroll
            for (int j = 0; j < 4; j++) fa[j] = *(const float4*)(ap + kb + 32 + 4 * j);
            if (addp) {
#pragma unroll
                for (int j = 0; j < 4; j++) fp[j] = *(const float4*)(pp + kb + 32 + 4 * j);
            }
            rb0 = *(const uint4*)(bp + kb + 32 + 0);
            rb1 = *(const uint4*)(bp + kb + 32 + 8);
        }

        short8 af[4], bfr[4];
#pragma unroll
        for (int mt = 0; mt < 4; mt++)
            af[mt] = *(const short8*)&Ash[wr * 64 + mt * 16 + lrow][quad * 8];
#pragma unroll
        for (int nt = 0; nt < 4; nt++)
            bfr[nt] = *(const short8*)&Bsh[wc * 64 + nt * 16 + lrow][quad * 8];
#pragma unroll
        for (int mt = 0; mt < 4; mt++)
#pragma unroll
            for (int nt = 0; nt < 4; nt++)
                acc[mt][nt] = __builtin_amdgcn_mfma_f32_16x16x32_bf16(
                    af[mt], bfr[nt], acc[mt][nt], 0, 0, 0);
    }

#pragma unroll
    for (int nt = 0; nt < 4; nt++) {
        const int col = col0 + wc * 64 + nt * 16 + lrow;
        const float bv = bias[col];
#pragma unroll
        for (int mt = 0; mt < 4; mt++) {
            f32x4 a = acc[mt][nt];
#pragma unroll
            for (int r = 0; r < 4; r++) {
                const int row = row0 + wr * 64 + mt * 16 + quad * 4 + r;
                float v = a[r] + bv;
                if (col < 256)
                    val[(size_t)row * 256 + col] = f2bf(v);
                else
                    qout[(size_t)row * 384 + (col - 256)] = v;
            }
        }
    }
}

// ---------------------------------------------------------------------------
// Two-phase sampler, 2 queries per block (256 thr = 2 x 128), ushort2 gathers.
// ---------------------------------------------------------------------------
__global__ void sampler(const unsigned short* __restrict__ val, const float* __restrict__ qout,
                        unsigned short* __restrict__ out) {
    __shared__ __align__(16) int   sIdx[2][128][4];
    __shared__ __align__(16) float sW[2][128][4];
    const int t = threadIdx.x;
    const int sub = t >> 7;
    const int tt = t & 127;
    const int bq = blockIdx.x * 2 + sub;
    const int b = bq / LEN, q = bq % LEN;

    {
        const int h = tt >> 4, p = tt & 15;
        const int l = p >> 2;

        float refx, refy;
        if (q < 4096) {
            int rq = q >> 6, cq = q & 63;
            refx = (cq + 0.5f) * (1.0f / 64.0f);
            refy = (rq + 0.5f) * (1.0f / 64.0f);
        } else if (q < 5120) {
            int qq = q - 4096;
            int rq = qq >> 5, cq = qq & 31;
            refx = (cq + 0.5f) * (1.0f / 32.0f);
            refy = (rq + 0.5f) * (1.0f / 32.0f);
        } else if (q < 5376) {
            int qq = q - 5120;
            int rq = qq >> 4, cq = qq & 15;
            refx = (cq + 0.5f) * (1.0f / 16.0f);
            refy = (rq + 0.5f) * (1.0f / 16.0f);
        } else {
            int qq = q - 5376;
            int rq = qq >> 3, cq = qq & 7;
            refx = (cq + 0.5f) * (1.0f / 8.0f);
            refy = (rq + 0.5f) * (1.0f / 8.0f);
        }

        float lv = qout[(size_t)bq * 384 + 256 + tt];
        float mx = lv;
#pragma unroll
        for (int o = 1; o < 16; o <<= 1) mx = fmaxf(mx, __shfl_xor(mx, o, 16));
        float e = expf(lv - mx);
        float s = e;
#pragma unroll
        for (int o = 1; o < 16; o <<= 1) s += __shfl_xor(s, o, 16);
        const float aw = e / s;

        const float ox = qout[(size_t)bq * 384 + h * 32 + p * 2 + 0];
        const float oy = qout[(size_t)bq * 384 + h * 32 + p * 2 + 1];

        const int LST[4] = {0, 4096, 5120, 5376};
        const int WW = 64 >> l;
        const float rw = 1.0f / (float)WW;

        float x = (refx + ox * rw) * (float)WW - 0.5f;
        float y = (refy + oy * rw) * (float)WW - 0.5f;
        float x0f = floorf(x), y0f = floorf(y);
        float dx = x - x0f, dy = y - y0f;
        int x0 = (int)x0f, y0 = (int)y0f;

        const int base = (b * LEN + LST[l]) * 256 + h * 32;
        int xs[2] = {x0, x0 + 1}, ys[2] = {y0, y0 + 1};
        float wx[2] = {1.f - dx, dx}, wy[2] = {1.f - dy, dy};
        int ic[4]; float wc4[4];
#pragma unroll
        for (int cy = 0; cy < 2; cy++)
#pragma unroll
            for (int cx = 0; cx < 2; cx++) {
                int xi = xs[cx], yi = ys[cy];
                bool vld = (xi >= 0) && (xi < WW) && (yi >= 0) && (yi < WW);
                int xc = min(max(xi, 0), WW - 1);
                int yc = min(max(yi, 0), WW - 1);
                ic[cy * 2 + cx] = base + (yc * WW + xc) * 256;
                wc4[cy * 2 + cx] = vld ? wx[cx] * wy[cy] * aw : 0.f;
            }
        *(int4*)&sIdx[sub][tt][0] = make_int4(ic[0], ic[1], ic[2], ic[3]);
        *(float4*)&sW[sub][tt][0] = make_float4(wc4[0], wc4[1], wc4[2], wc4[3]);
    }
    __syncthreads();

    const int h = tt >> 4, dp = tt & 15;
    const unsigned short* vald = val + 2 * dp;
    float acc0 = 0.f, acc1 = 0.f;
#pragma unroll 4
    for (int p = 0; p < 16; p++) {
        const int r = h * 16 + p;
        int4 iv = *(const int4*)&sIdx[sub][r][0];
        float4 wv = *(const float4*)&sW[sub][r][0];
        uint32 u0 = *(const uint32*)(vald + iv.x);
        uint32 u1 = *(const uint32*)(vald + iv.y);
        uint32 u2 = *(const uint32*)(vald + iv.z);
        uint32 u3 = *(const uint32*)(vald + iv.w);
        acc0 += bf2f((unsigned short)u0) * wv.x + bf2f((unsigned short)u1) * wv.y +
                bf2f((unsigned short)u2) * wv.z + bf2f((unsigned short)u3) * wv.w;
        acc1 += bf2f((unsigned short)(u0 >> 16)) * wv.x + bf2f((unsigned short)(u1 >> 16)) * wv.y +
                bf2f((unsigned short)(u2 >> 16)) * wv.z + bf2f((unsigned short)(u3 >> 16)) * wv.w;
    }
    *(uint32*)&out[(size_t)bq * D + h * HD + 2 * dp] = pack2(acc0, acc1);
}

// ---------------------------------------------------------------------------
// out = LayerNorm(sum_z part16[z] + bias + rsd) * g + be  (one row per block)
// part16: bf16 split-K partials.
// ---------------------------------------------------------------------------
template <int NPART>
__global__ void add_lnN(const unsigned short* __restrict__ part16,
                        const float* __restrict__ bias, const float* __restrict__ rsd,
                        const float* __restrict__ g, const float* __restrict__ be,
                        float* __restrict__ out, unsigned short* __restrict__ out16) {
    __shared__ float r1[4], r2[4];
    const int row = blockIdx.x, t = threadIdx.x;
    const size_t i = (size_t)row * D + t;
    float v = bias[t] + rsd[i];
#pragma unroll
    for (int z = 0; z < NPART; z++) v += bf2f(part16[(size_t)z * MROWS * 256 + i]);
    float s1 = v, s2 = v * v;
#pragma unroll
    for (int o = 32; o > 0; o >>= 1) {
        s1 += __shfl_down(s1, o, 64);
        s2 += __shfl_down(s2, o, 64);
    }
    if ((t & 63) == 0) { r1[t >> 6] = s1; r2[t >> 6] = s2; }
    __syncthreads();
    float su = r1[0] + r1[1] + r1[2] + r1[3];
    float sq = r2[0] + r2[1] + r2[2] + r2[3];
    float mean = su * (1.0f / D);
    float var = fmaxf(sq * (1.0f / D) - mean * mean, 0.f);
    const float o = (v - mean) * rsqrtf(var + 1e-5f) * g[t] + be[t];
    out[i] = o;
    if (out16) out16[i] = f2bf(o);
}

// ---------------------------------------------------------------------------
extern "C" void kernel_launch(void* const* d_in, const int* in_sizes, int n_in,
                              void* d_out, int out_size, void* d_ws, size_t ws_size,
                              hipStream_t stream) {
    const float* src     = (const float*)d_in[0];
    const float* pos     = (const float*)d_in[1];
    const float* w_value = (const float*)d_in[4];
    const float* b_value = (const float*)d_in[5];
    const float* w_off   = (const float*)d_in[6];
    const float* b_off   = (const float*)d_in[7];
    const float* w_attn  = (const float*)d_in[8];
    const float* b_attn  = (const float*)d_in[9];
    const float* w_out   = (const float*)d_in[10];
    const float* b_out   = (const float*)d_in[11];
    const float* w1      = (const float*)d_in[12];
    const float* b1      = (const float*)d_in[13];
    const float* w2      = (const float*)d_in[14];
    const float* b2      = (const float*)d_in[15];
    const float* g1      = (const float*)d_in[16];
    const float* be1     = (const float*)d_in[17];
    const float* g2      = (const float*)d_in[18];
    const float* be2     = (const float*)d_in[19];
    float* out = (float*)d_out;

    // ---- workspace layout (~112 MB of the 256 MiB ws) ----
    size_t off = 0;
    auto alloc = [&](size_t bytes) -> char* {
        char* p = (char*)d_ws + off;
        off += (bytes + 255) & ~(size_t)255;
        return p;
    };
    unsigned short* wqvT = (unsigned short*)alloc((size_t)640 * 256 * 2);
    unsigned short* woT  = (unsigned short*)alloc(256 * 256 * 2);
    unsigned short* w1T  = (unsigned short*)alloc((size_t)2048 * 256 * 2);
    unsigned short* w2T  = (unsigned short*)alloc((size_t)256 * 2048 * 2);
    float* bqv           = (float*)alloc(640 * 4);

    float* qout          = (float*)alloc((size_t)MROWS * 384 * 4);   // 16.71 MB
    unsigned short* val  = (unsigned short*)alloc((size_t)MROWS * 256 * 2);
    unsigned short* attn = (unsigned short*)alloc((size_t)MROWS * 256 * 2);
    unsigned short* hb   = (unsigned short*)alloc((size_t)MROWS * 2048 * 2);  // 44.6 MB
    float* xbuf          = (float*)alloc((size_t)MROWS * 256 * 4);
    unsigned short* xb16 = (unsigned short*)alloc((size_t)MROWS * 256 * 2);
    unsigned short* part = (unsigned short*)alloc((size_t)4 * MROWS * 256 * 2); // 22.3 MB

    // ---- weight prep (single launch) ----
    prep<<<1249, 256, 0, stream>>>(w_value, w_off, w_attn, w_out, w1, w2,
                                   b_value, b_off, b_attn, wqvT, woT, w1T, w2T, bqv);

    // ---- attention ----
    qv_gemm<<<425, 256, 0, stream>>>(src, pos, wqvT, bqv, val, qout);
    sampler<<<MROWS / 2, 256, 0, stream>>>(val, qout, attn);
    // x = LN(attn @ w_out + b_out + src) -> xbuf + xb16   (fused, K=256)
    gemm_ln<true><<<340, 256, 0, stream>>>(attn, woT, b_out, src, g1, be1,
                                           xbuf, xb16, 256);

    // ---- FFN (unfused ffn2: splitk 680 blocks, bf16 partials + add_ln) ----
    ffn1_gemm<<<1360, 256, 0, stream>>>(xb16, w1T, b1, hb, 2048, 256, 256, 256);
    splitk_gemm<4><<<680, 256, 0, stream>>>(hb, w2T, part, 512, 2048, 2048);
    add_lnN<4><<<MROWS, 256, 0, stream>>>(part, b2, xbuf, g2, be2, out, nullptr);
}

// Round 14
// 205.598 us; speedup vs baseline: 1.0353x; 1.0353x over previous
//
#include <hip/hip_runtime.h>
#include <math.h>

#define D 256
#define NH 8
#define NL 4
#define NP 4
#define DFF 2048
#define HD 32
#define BB 2
#define LEN 5440
#define MROWS (BB * LEN)   // 10880 = 85*128 = 340*32 = 2720*4

typedef __attribute__((ext_vector_type(8))) short short8;
typedef __attribute__((ext_vector_type(4))) float f32x4;
typedef unsigned int uint32;

__device__ __forceinline__ unsigned short f2bf(float f) {
    uint32 u = __float_as_uint(f);
    u += 0x7FFF + ((u >> 16) & 1);           // round-to-nearest-even
    return (unsigned short)(u >> 16);
}
__device__ __forceinline__ float bf2f(unsigned short h) {
    return __uint_as_float(((uint32)h) << 16);
}
__device__ __forceinline__ uint32 pack2(float a, float b) {
    return (uint32)f2bf(a) | ((uint32)f2bf(b) << 16);
}

// XCD-affinity swizzle: 85 row-tiles x ncols col-tiles.
__device__ __forceinline__ void swz85(int b, int ncols, int& row, int& col) {
    const int gsz = ncols << 3;
    const int full = 10 * gsz;
    if (b < full) {
        const int g = b / gsz, idx = b - g * gsz;
        row = (g << 3) + (idx & 7);
        col = idx >> 3;
    } else {
        const int idx = b - full;
        row = 80 + idx % 5;
        col = idx / 5;
    }
}

// ---------------------------------------------------------------------------
// prep: all weight transposes (fp32 [KxN] -> bf16 [NxK]) + bias concat.
// ---------------------------------------------------------------------------
__global__ void prep(const float* __restrict__ w_value, const float* __restrict__ w_off,
                     const float* __restrict__ w_attn, const float* __restrict__ w_out,
                     const float* __restrict__ w1, const float* __restrict__ w2,
                     const float* __restrict__ b_value, const float* __restrict__ b_off,
                     const float* __restrict__ b_attn,
                     unsigned short* __restrict__ wqvT, unsigned short* __restrict__ woT,
                     unsigned short* __restrict__ w1T, unsigned short* __restrict__ w2T,
                     float* __restrict__ bqv) {
    const int blk = blockIdx.x;
    if (blk >= 1248) {
        for (int i = threadIdx.x; i < 640; i += 256)
            bqv[i] = (i < 256) ? b_value[i] : (i < 512 ? b_off[i - 256] : b_attn[i - 512]);
        return;
    }
    const float* W; unsigned short* WT; int K, N, tid;
    if (blk < 64)       { W = w_value; WT = wqvT;             K = 256;  N = 256;  tid = blk; }
    else if (blk < 128) { W = w_off;   WT = wqvT + 256 * 256; K = 256;  N = 256;  tid = blk - 64; }
    else if (blk < 160) { W = w_attn;  WT = wqvT + 512 * 256; K = 256;  N = 128;  tid = blk - 128; }
    else if (blk < 224) { W = w_out;   WT = woT;              K = 256;  N = 256;  tid = blk - 160; }
    else if (blk < 736) { W = w1;      WT = w1T;              K = 256;  N = 2048; tid = blk - 224; }
    else                { W = w2;      WT = w2T;              K = 2048; N = 256;  tid = blk - 736; }
    const int ntx = N >> 5;
    const int nb = (tid % ntx) * 32, kb = (tid / ntx) * 32;

    __shared__ float tile[32][33];
    const int tx = threadIdx.x & 31, ty = threadIdx.x >> 5;
#pragma unroll
    for (int i = 0; i < 32; i += 8)
        tile[ty + i][tx] = W[(size_t)(kb + ty + i) * N + nb + tx];
    __syncthreads();
#pragma unroll
    for (int i = 0; i < 32; i += 8)
        WT[(size_t)(nb + ty + i) * K + kb + tx] = f2bf(tile[tx][ty + i]);
}

// ---------------------------------------------------------------------------
// ffn1 GEMM: C = relu(A @ BT^T + bias) -> bf16. 128x128 tile, pipelined.
// ---------------------------------------------------------------------------
__global__ __launch_bounds__(256) void ffn1_gemm(
        const unsigned short* __restrict__ A,
        const unsigned short* __restrict__ BT, const float* __restrict__ bias,
        unsigned short* __restrict__ Cv, int N, int K, int lda, int ldb) {
    __shared__ unsigned short Ash[128][40];
    __shared__ unsigned short Bsh[128][40];

    int rowt, colt;
    swz85(blockIdx.x, N >> 7, rowt, colt);
    const int row0 = rowt * 128, col0 = colt * 128;

    const int t = threadIdx.x;
    const int wave = t >> 6, lane = t & 63;
    const int wr = wave >> 1, wc = wave & 1;
    const int lrow = lane & 15, quad = lane >> 4;
    const int srow = t >> 1;
    const int cb = (t & 1) * 16;

    const unsigned short* ap = A + (size_t)(row0 + srow) * lda + cb;
    const unsigned short* bp = BT + (size_t)(col0 + srow) * ldb + cb;

    f32x4 acc[4][4];
#pragma unroll
    for (int i = 0; i < 4; i++)
#pragma unroll
        for (int j = 0; j < 4; j++) acc[i][j] = (f32x4){0.f, 0.f, 0.f, 0.f};

    uint4 ra0 = *(const uint4*)(ap + 0), ra1 = *(const uint4*)(ap + 8);
    uint4 rb0 = *(const uint4*)(bp + 0), rb1 = *(const uint4*)(bp + 8);

    for (int kb = 0; kb < K; kb += 32) {
        __syncthreads();
        *(uint4*)&Ash[srow][cb + 0] = ra0;
        *(uint4*)&Ash[srow][cb + 8] = ra1;
        *(uint4*)&Bsh[srow][cb + 0] = rb0;
        *(uint4*)&Bsh[srow][cb + 8] = rb1;
        __syncthreads();
        if (kb + 32 < K) {
            ra0 = *(const uint4*)(ap + kb + 32 + 0);
            ra1 = *(const uint4*)(ap + kb + 32 + 8);
            rb0 = *(const uint4*)(bp + kb + 32 + 0);
            rb1 = *(const uint4*)(bp + kb + 32 + 8);
        }

        short8 af[4], bfr[4];
#pragma unroll
        for (int mt = 0; mt < 4; mt++)
            af[mt] = *(const short8*)&Ash[wr * 64 + mt * 16 + lrow][quad * 8];
#pragma unroll
        for (int nt = 0; nt < 4; nt++)
            bfr[nt] = *(const short8*)&Bsh[wc * 64 + nt * 16 + lrow][quad * 8];
#pragma unroll
        for (int mt = 0; mt < 4; mt++)
#pragma unroll
            for (int nt = 0; nt < 4; nt++)
                acc[mt][nt] = __builtin_amdgcn_mfma_f32_16x16x32_bf16(
                    af[mt], bfr[nt], acc[mt][nt], 0, 0, 0);
    }

#pragma unroll
    for (int nt = 0; nt < 4; nt++) {
        const int col = col0 + wc * 64 + nt * 16 + lrow;
        const float bv = bias[col];
#pragma unroll
        for (int mt = 0; mt < 4; mt++) {
            f32x4 a = acc[mt][nt];
#pragma unroll
            for (int r = 0; r < 4; r++) {
                const int row = row0 + wr * 64 + mt * 16 + quad * 4 + r;
                Cv[(size_t)row * N + col] = f2bf(fmaxf(a[r] + bv, 0.f));
            }
        }
    }
}

// ---------------------------------------------------------------------------
// Split-K GEMM (N=256): partial[z] = A[:, z*KC:] @ BT[:, z*KC:]^T, bf16 out.
// ---------------------------------------------------------------------------
template <int NZ>
__global__ __launch_bounds__(256) void splitk_gemm(
        const unsigned short* __restrict__ A, const unsigned short* __restrict__ BT,
        unsigned short* __restrict__ part, int KC, int lda, int ldb) {
    __shared__ unsigned short Ash[128][40];
    __shared__ unsigned short Bsh[128][40];

    int rowt, cc;
    swz85(blockIdx.x, 2 * NZ, rowt, cc);
    const int row0 = rowt * 128;
    const int col0 = (cc & 1) * 128;
    const int z = cc >> 1;
    const int koff = z * KC;
    unsigned short* __restrict__ C = part + (size_t)z * MROWS * 256;

    const int t = threadIdx.x;
    const int wave = t >> 6, lane = t & 63;
    const int wr = wave >> 1, wc = wave & 1;
    const int lrow = lane & 15, quad = lane >> 4;
    const int srow = t >> 1;
    const int cb = (t & 1) * 16;

    const unsigned short* ap = A + (size_t)(row0 + srow) * lda + koff + cb;
    const unsigned short* bp = BT + (size_t)(col0 + srow) * ldb + koff + cb;

    f32x4 acc[4][4];
#pragma unroll
    for (int i = 0; i < 4; i++)
#pragma unroll
        for (int j = 0; j < 4; j++) acc[i][j] = (f32x4){0.f, 0.f, 0.f, 0.f};

    uint4 ra0 = *(const uint4*)(ap + 0), ra1 = *(const uint4*)(ap + 8);
    uint4 rb0 = *(const uint4*)(bp + 0), rb1 = *(const uint4*)(bp + 8);

    for (int kb = 0; kb < KC; kb += 32) {
        __syncthreads();
        *(uint4*)&Ash[srow][cb + 0] = ra0;
        *(uint4*)&Ash[srow][cb + 8] = ra1;
        *(uint4*)&Bsh[srow][cb + 0] = rb0;
        *(uint4*)&Bsh[srow][cb + 8] = rb1;
        __syncthreads();
        if (kb + 32 < KC) {
            ra0 = *(const uint4*)(ap + kb + 32 + 0);
            ra1 = *(const uint4*)(ap + kb + 32 + 8);
            rb0 = *(const uint4*)(bp + kb + 32 + 0);
            rb1 = *(const uint4*)(bp + kb + 32 + 8);
        }

        short8 af[4], bfr[4];
#pragma unroll
        for (int mt = 0; mt < 4; mt++)
            af[mt] = *(const short8*)&Ash[wr * 64 + mt * 16 + lrow][quad * 8];
#pragma unroll
        for (int nt = 0; nt < 4; nt++)
            bfr[nt] = *(const short8*)&Bsh[wc * 64 + nt * 16 + lrow][quad * 8];
#pragma unroll
        for (int mt = 0; mt < 4; mt++)
#pragma unroll
            for (int nt = 0; nt < 4; nt++)
                acc[mt][nt] = __builtin_amdgcn_mfma_f32_16x16x32_bf16(
                    af[mt], bfr[nt], acc[mt][nt], 0, 0, 0);
    }

#pragma unroll
    for (int nt = 0; nt < 4; nt++) {
        const int col = col0 + wc * 64 + nt * 16 + lrow;
#pragma unroll
        for (int mt = 0; mt < 4; mt++) {
            f32x4 a = acc[mt][nt];
#pragma unroll
            for (int r = 0; r < 4; r++) {
                const int row = row0 + wr * 64 + mt * 16 + quad * 4 + r;
                C[(size_t)row * 256 + col] = f2bf(a[r]);
            }
        }
    }
}

// ---------------------------------------------------------------------------
// Fused GEMM + bias + residual + LayerNorm (K=256 proj). Output: bf16 only.
// Tile 32 rows x 256 cols, full K. Grid = M/32 = 340.
// ---------------------------------------------------------------------------
__global__ __launch_bounds__(256) void gemm_ln(
        const unsigned short* __restrict__ A, const unsigned short* __restrict__ BT,
        const float* __restrict__ bias, const float* __restrict__ rsd,
        const float* __restrict__ g, const float* __restrict__ be,
        unsigned short* __restrict__ out16, int K) {
    __shared__ __align__(16) unsigned short Ash[32][40];
    __shared__ __align__(16) unsigned short Bsh[256][40];
    __shared__ float red1[4][32], red2[4][32];

    const int row0 = blockIdx.x * 32;
    const int t = threadIdx.x;
    const int wave = t >> 6, lane = t & 63;
    const int lrow = lane & 15, quad = lane >> 4;

    const int ar = t >> 3, ac = (t & 7) * 4;
    const unsigned short* ap = A + (size_t)(row0 + ar) * K + ac;
    const int br = t >> 1, cb = (t & 1) * 16;
    const unsigned short* bp0 = BT + (size_t)br * K + cb;
    const unsigned short* bp1 = BT + (size_t)(128 + br) * K + cb;

    f32x4 acc[2][4];
#pragma unroll
    for (int i = 0; i < 2; i++)
#pragma unroll
        for (int j = 0; j < 4; j++) acc[i][j] = (f32x4){0.f, 0.f, 0.f, 0.f};

    uint2 ra = *(const uint2*)ap;
    uint4 rb00 = *(const uint4*)(bp0 + 0), rb01 = *(const uint4*)(bp0 + 8);
    uint4 rb10 = *(const uint4*)(bp1 + 0), rb11 = *(const uint4*)(bp1 + 8);

    for (int kb = 0; kb < K; kb += 32) {
        __syncthreads();
        *(uint2*)&Ash[ar][ac] = ra;
        *(uint4*)&Bsh[br][cb + 0] = rb00;
        *(uint4*)&Bsh[br][cb + 8] = rb01;
        *(uint4*)&Bsh[128 + br][cb + 0] = rb10;
        *(uint4*)&Bsh[128 + br][cb + 8] = rb11;
        __syncthreads();
        if (kb + 32 < K) {
            ra   = *(const uint2*)(ap + kb + 32);
            rb00 = *(const uint4*)(bp0 + kb + 32 + 0);
            rb01 = *(const uint4*)(bp0 + kb + 32 + 8);
            rb10 = *(const uint4*)(bp1 + kb + 32 + 0);
            rb11 = *(const uint4*)(bp1 + kb + 32 + 8);
        }

        short8 af[2], bfr[4];
#pragma unroll
        for (int mt = 0; mt < 2; mt++)
            af[mt] = *(const short8*)&Ash[mt * 16 + lrow][quad * 8];
#pragma unroll
        for (int nt = 0; nt < 4; nt++)
            bfr[nt] = *(const short8*)&Bsh[wave * 64 + nt * 16 + lrow][quad * 8];
#pragma unroll
        for (int mt = 0; mt < 2; mt++)
#pragma unroll
            for (int nt = 0; nt < 4; nt++)
                acc[mt][nt] = __builtin_amdgcn_mfma_f32_16x16x32_bf16(
                    af[mt], bfr[nt], acc[mt][nt], 0, 0, 0);
    }

    float gv[4], bev[4], bv[4];
#pragma unroll
    for (int nt = 0; nt < 4; nt++) {
        const int col = wave * 64 + nt * 16 + lrow;
        bv[nt] = bias[col];
        gv[nt] = g[col];
        bev[nt] = be[col];
    }

    float v[2][4][4];
#pragma unroll
    for (int mt = 0; mt < 2; mt++)
#pragma unroll
        for (int r = 0; r < 4; r++) {
            const int row = row0 + mt * 16 + quad * 4 + r;
#pragma unroll
            for (int nt = 0; nt < 4; nt++) {
                const int col = wave * 64 + nt * 16 + lrow;
                v[mt][nt][r] = acc[mt][nt][r] + bv[nt] + rsd[(size_t)row * 256 + col];
            }
        }

#pragma unroll
    for (int mt = 0; mt < 2; mt++)
#pragma unroll
        for (int r = 0; r < 4; r++) {
            float s1 = v[mt][0][r] + v[mt][1][r] + v[mt][2][r] + v[mt][3][r];
            float s2 = v[mt][0][r] * v[mt][0][r] + v[mt][1][r] * v[mt][1][r] +
                       v[mt][2][r] * v[mt][2][r] + v[mt][3][r] * v[mt][3][r];
#pragma unroll
            for (int o = 1; o < 16; o <<= 1) {
                s1 += __shfl_xor(s1, o, 16);
                s2 += __shfl_xor(s2, o, 16);
            }
            if (lrow == 0) {
                const int rr = mt * 16 + quad * 4 + r;
                red1[wave][rr] = s1;
                red2[wave][rr] = s2;
            }
        }
    __syncthreads();

#pragma unroll
    for (int mt = 0; mt < 2; mt++)
#pragma unroll
        for (int r = 0; r < 4; r++) {
            const int rr = mt * 16 + quad * 4 + r;
            const float su = red1[0][rr] + red1[1][rr] + red1[2][rr] + red1[3][rr];
            const float sq = red2[0][rr] + red2[1][rr] + red2[2][rr] + red2[3][rr];
            const float mean = su * (1.0f / 256.0f);
            const float var = fmaxf(sq * (1.0f / 256.0f) - mean * mean, 0.f);
            const float rstd = rsqrtf(var + 1e-5f);
            const size_t rowoff = (size_t)(row0 + rr) * 256;
#pragma unroll
            for (int nt = 0; nt < 4; nt++) {
                const int col = wave * 64 + nt * 16 + lrow;
                const float o = (v[mt][nt][r] - mean) * rstd * gv[nt] + bev[nt];
                out16[rowoff + col] = f2bf(o);
            }
        }
}

// ---------------------------------------------------------------------------
// Merged value+query GEMM: flat grid 425 = 85 rows x 5 cols, swizzled.
// col < 256 -> val (bf16); col >= 256 -> qout16 (bf16, stride 384).
// ---------------------------------------------------------------------------
__global__ __launch_bounds__(256) void qv_gemm(
        const float* __restrict__ src, const float* __restrict__ pos,
        const unsigned short* __restrict__ BT, const float* __restrict__ bias,
        unsigned short* __restrict__ val, unsigned short* __restrict__ qout16) {
    __shared__ unsigned short Ash[128][40];
    __shared__ unsigned short Bsh[128][40];

    int rowt, colt;
    swz85(blockIdx.x, 5, rowt, colt);
    const int row0 = rowt * 128, col0 = colt * 128;
    const bool addp = (col0 >= 256);

    const int t = threadIdx.x;
    const int wave = t >> 6, lane = t & 63;
    const int wr = wave >> 1, wc = wave & 1;
    const int lrow = lane & 15, quad = lane >> 4;
    const int srow = t >> 1;
    const int cb = (t & 1) * 16;

    const float* ap = src + (size_t)(row0 + srow) * 256 + cb;
    const float* pp = pos + (size_t)(row0 + srow) * 256 + cb;
    const unsigned short* bp = BT + (size_t)(col0 + srow) * 256 + cb;

    f32x4 acc[4][4];
#pragma unroll
    for (int i = 0; i < 4; i++)
#pragma unroll
        for (int j = 0; j < 4; j++) acc[i][j] = (f32x4){0.f, 0.f, 0.f, 0.f};

    float4 fa[4]; float4 fp[4]; uint4 rb0, rb1;
#pragma unroll
    for (int j = 0; j < 4; j++) fa[j] = *(const float4*)(ap + 4 * j);
    if (addp) {
#pragma unroll
        for (int j = 0; j < 4; j++) fp[j] = *(const float4*)(pp + 4 * j);
    }
    rb0 = *(const uint4*)(bp + 0);
    rb1 = *(const uint4*)(bp + 8);

    for (int kb = 0; kb < 256; kb += 32) {
        __syncthreads();
        {
            float4 f0 = fa[0], f1 = fa[1], f2 = fa[2], f3 = fa[3];
            if (addp) {
                f0.x += fp[0].x; f0.y += fp[0].y; f0.z += fp[0].z; f0.w += fp[0].w;
                f1.x += fp[1].x; f1.y += fp[1].y; f1.z += fp[1].z; f1.w += fp[1].w;
                f2.x += fp[2].x; f2.y += fp[2].y; f2.z += fp[2].z; f2.w += fp[2].w;
                f3.x += fp[3].x; f3.y += fp[3].y; f3.z += fp[3].z; f3.w += fp[3].w;
            }
            uint4 u0 = make_uint4(pack2(f0.x, f0.y), pack2(f0.z, f0.w),
                                  pack2(f1.x, f1.y), pack2(f1.z, f1.w));
            uint4 u1 = make_uint4(pack2(f2.x, f2.y), pack2(f2.z, f2.w),
                                  pack2(f3.x, f3.y), pack2(f3.z, f3.w));
            *(uint4*)&Ash[srow][cb + 0] = u0;
            *(uint4*)&Ash[srow][cb + 8] = u1;
            *(uint4*)&Bsh[srow][cb + 0] = rb0;
            *(uint4*)&Bsh[srow][cb + 8] = rb1;
        }
        __syncthreads();
        if (kb + 32 < 256) {
#pragma unroll
            for (int j = 0; j < 4; j++) fa[j] = *(const float4*)(ap + kb + 32 + 4 * j);
            if (addp) {
#pragma unroll
                for (int j = 0; j < 4; j++) fp[j] = *(const float4*)(pp + kb + 32 + 4 * j);
            }
            rb0 = *(const uint4*)(bp + kb + 32 + 0);
            rb1 = *(const uint4*)(bp + kb + 32 + 8);
        }

        short8 af[4], bfr[4];
#pragma unroll
        for (int mt = 0; mt < 4; mt++)
            af[mt] = *(const short8*)&Ash[wr * 64 + mt * 16 + lrow][quad * 8];
#pragma unroll
        for (int nt = 0; nt < 4; nt++)
            bfr[nt] = *(const short8*)&Bsh[wc * 64 + nt * 16 + lrow][quad * 8];
#pragma unroll
        for (int mt = 0; mt < 4; mt++)
#pragma unroll
            for (int nt = 0; nt < 4; nt++)
                acc[mt][nt] = __builtin_amdgcn_mfma_f32_16x16x32_bf16(
                    af[mt], bfr[nt], acc[mt][nt], 0, 0, 0);
    }

#pragma unroll
    for (int nt = 0; nt < 4; nt++) {
        const int col = col0 + wc * 64 + nt * 16 + lrow;
        const float bv = bias[col];
#pragma unroll
        for (int mt = 0; mt < 4; mt++) {
            f32x4 a = acc[mt][nt];
#pragma unroll
            for (int r = 0; r < 4; r++) {
                const int row = row0 + wr * 64 + mt * 16 + quad * 4 + r;
                float v = a[r] + bv;
                if (col < 256)
                    val[(size_t)row * 256 + col] = f2bf(v);
                else
                    qout16[(size_t)row * 384 + (col - 256)] = f2bf(v);
            }
        }
    }
}

// ---------------------------------------------------------------------------
// Two-phase sampler, 2 queries per block, ushort2 gathers; qout in bf16.
// ---------------------------------------------------------------------------
__global__ void sampler(const unsigned short* __restrict__ val,
                        const unsigned short* __restrict__ qout16,
                        unsigned short* __restrict__ out) {
    __shared__ __align__(16) int   sIdx[2][128][4];
    __shared__ __align__(16) float sW[2][128][4];
    const int t = threadIdx.x;
    const int sub = t >> 7;
    const int tt = t & 127;
    const int bq = blockIdx.x * 2 + sub;
    const int b = bq / LEN, q = bq % LEN;

    {
        const int h = tt >> 4, p = tt & 15;
        const int l = p >> 2;

        float refx, refy;
        if (q < 4096) {
            int rq = q >> 6, cq = q & 63;
            refx = (cq + 0.5f) * (1.0f / 64.0f);
            refy = (rq + 0.5f) * (1.0f / 64.0f);
        } else if (q < 5120) {
            int qq = q - 4096;
            int rq = qq >> 5, cq = qq & 31;
            refx = (cq + 0.5f) * (1.0f / 32.0f);
            refy = (rq + 0.5f) * (1.0f / 32.0f);
        } else if (q < 5376) {
            int qq = q - 5120;
            int rq = qq >> 4, cq = qq & 15;
            refx = (cq + 0.5f) * (1.0f / 16.0f);
            refy = (rq + 0.5f) * (1.0f / 16.0f);
        } else {
            int qq = q - 5376;
            int rq = qq >> 3, cq = qq & 7;
            refx = (cq + 0.5f) * (1.0f / 8.0f);
            refy = (rq + 0.5f) * (1.0f / 8.0f);
        }

        float lv = bf2f(qout16[(size_t)bq * 384 + 256 + tt]);
        float mx = lv;
#pragma unroll
        for (int o = 1; o < 16; o <<= 1) mx = fmaxf(mx, __shfl_xor(mx, o, 16));
        float e = expf(lv - mx);
        float s = e;
#pragma unroll
        for (int o = 1; o < 16; o <<= 1) s += __shfl_xor(s, o, 16);
        const float aw = e / s;

        const uint32 opair = *(const uint32*)&qout16[(size_t)bq * 384 + h * 32 + p * 2];
        const float ox = bf2f((unsigned short)opair);
        const float oy = bf2f((unsigned short)(opair >> 16));

        const int LST[4] = {0, 4096, 5120, 5376};
        const int WW = 64 >> l;
        const float rw = 1.0f / (float)WW;

        float x = (refx + ox * rw) * (float)WW - 0.5f;
        float y = (refy + oy * rw) * (float)WW - 0.5f;
        float x0f = floorf(x), y0f = floorf(y);
        float dx = x - x0f, dy = y - y0f;
        int x0 = (int)x0f, y0 = (int)y0f;

        const int base = (b * LEN + LST[l]) * 256 + h * 32;
        int xs[2] = {x0, x0 + 1}, ys[2] = {y0, y0 + 1};
        float wx[2] = {1.f - dx, dx}, wy[2] = {1.f - dy, dy};
        int ic[4]; float wc4[4];
#pragma unroll
        for (int cy = 0; cy < 2; cy++)
#pragma unroll
            for (int cx = 0; cx < 2; cx++) {
                int xi = xs[cx], yi = ys[cy];
                bool vld = (xi >= 0) && (xi < WW) && (yi >= 0) && (yi < WW);
                int xc = min(max(xi, 0), WW - 1);
                int yc = min(max(yi, 0), WW - 1);
                ic[cy * 2 + cx] = base + (yc * WW + xc) * 256;
                wc4[cy * 2 + cx] = vld ? wx[cx] * wy[cy] * aw : 0.f;
            }
        *(int4*)&sIdx[sub][tt][0] = make_int4(ic[0], ic[1], ic[2], ic[3]);
        *(float4*)&sW[sub][tt][0] = make_float4(wc4[0], wc4[1], wc4[2], wc4[3]);
    }
    __syncthreads();

    const int h = tt >> 4, dp = tt & 15;
    const unsigned short* vald = val + 2 * dp;
    float acc0 = 0.f, acc1 = 0.f;
#pragma unroll 4
    for (int p = 0; p < 16; p++) {
        const int r = h * 16 + p;
        int4 iv = *(const int4*)&sIdx[sub][r][0];
        float4 wv = *(const float4*)&sW[sub][r][0];
        uint32 u0 = *(const uint32*)(vald + iv.x);
        uint32 u1 = *(const uint32*)(vald + iv.y);
        uint32 u2 = *(const uint32*)(vald + iv.z);
        uint32 u3 = *(const uint32*)(vald + iv.w);
        acc0 += bf2f((unsigned short)u0) * wv.x + bf2f((unsigned short)u1) * wv.y +
                bf2f((unsigned short)u2) * wv.z + bf2f((unsigned short)u3) * wv.w;
        acc1 += bf2f((unsigned short)(u0 >> 16)) * wv.x + bf2f((unsigned short)(u1 >> 16)) * wv.y +
                bf2f((unsigned short)(u2 >> 16)) * wv.z + bf2f((unsigned short)(u3 >> 16)) * wv.w;
    }
    *(uint32*)&out[(size_t)bq * D + h * HD + 2 * dp] = pack2(acc0, acc1);
}

// ---------------------------------------------------------------------------
// Final LN, wave-per-row (no __syncthreads): out = LN(sum_z part16[z] + bias
// + rsd16) * g + be. Grid = M/4, block 256 = 4 waves = 4 rows.
// ---------------------------------------------------------------------------
__global__ void add_ln4(const unsigned short* __restrict__ part16,
                        const float* __restrict__ bias,
                        const unsigned short* __restrict__ rsd16,
                        const float* __restrict__ g, const float* __restrict__ be,
                        float* __restrict__ out) {
    const int wave = threadIdx.x >> 6, lane = threadIdx.x & 63;
    const int row = blockIdx.x * 4 + wave;
    const int c0 = lane * 4;
    const size_t i = (size_t)row * 256 + c0;

    float v[4];
    {
        ushort4 r = *(const ushort4*)&rsd16[i];
        float4 bv = *(const float4*)&bias[c0];
        v[0] = bf2f(r.x) + bv.x; v[1] = bf2f(r.y) + bv.y;
        v[2] = bf2f(r.z) + bv.z; v[3] = bf2f(r.w) + bv.w;
    }
#pragma unroll
    for (int z = 0; z < 4; z++) {
        ushort4 p = *(const ushort4*)&part16[(size_t)z * MROWS * 256 + i];
        v[0] += bf2f(p.x); v[1] += bf2f(p.y); v[2] += bf2f(p.z); v[3] += bf2f(p.w);
    }
    float s1 = v[0] + v[1] + v[2] + v[3];
    float s2 = v[0] * v[0] + v[1] * v[1] + v[2] * v[2] + v[3] * v[3];
#pragma unroll
    for (int o = 32; o > 0; o >>= 1) {
        s1 += __shfl_xor(s1, o, 64);
        s2 += __shfl_xor(s2, o, 64);
    }
    const float mean = s1 * (1.0f / 256.0f);
    const float var = fmaxf(s2 * (1.0f / 256.0f) - mean * mean, 0.f);
    const float rstd = rsqrtf(var + 1e-5f);

    float4 gv = *(const float4*)&g[c0];
    float4 bev = *(const float4*)&be[c0];
    float4 o4;
    o4.x = (v[0] - mean) * rstd * gv.x + bev.x;
    o4.y = (v[1] - mean) * rstd * gv.y + bev.y;
    o4.z = (v[2] - mean) * rstd * gv.z + bev.z;
    o4.w = (v[3] - mean) * rstd * gv.w + bev.w;
    *(float4*)&out[i] = o4;
}

// ---------------------------------------------------------------------------
extern "C" void kernel_launch(void* const* d_in, const int* in_sizes, int n_in,
                              void* d_out, int out_size, void* d_ws, size_t ws_size,
                              hipStream_t stream) {
    const float* src     = (const float*)d_in[0];
    const float* pos     = (const float*)d_in[1];
    const float* w_value = (const float*)d_in[4];
    const float* b_value = (const float*)d_in[5];
    const float* w_off   = (const float*)d_in[6];
    const float* b_off   = (const float*)d_in[7];
    const float* w_attn  = (const float*)d_in[8];
    const float* b_attn  = (const float*)d_in[9];
    const float* w_out   = (const float*)d_in[10];
    const float* b_out   = (const float*)d_in[11];
    const float* w1      = (const float*)d_in[12];
    const float* b1      = (const float*)d_in[13];
    const float* w2      = (const float*)d_in[14];
    const float* b2      = (const float*)d_in[15];
    const float* g1      = (const float*)d_in[16];
    const float* be1     = (const float*)d_in[17];
    const float* g2      = (const float*)d_in[18];
    const float* be2     = (const float*)d_in[19];
    float* out = (float*)d_out;

    // ---- workspace layout (~95 MB of the 256 MiB ws) ----
    size_t off = 0;
    auto alloc = [&](size_t bytes) -> char* {
        char* p = (char*)d_ws + off;
        off += (bytes + 255) & ~(size_t)255;
        return p;
    };
    unsigned short* wqvT = (unsigned short*)alloc((size_t)640 * 256 * 2);
    unsigned short* woT  = (unsigned short*)alloc(256 * 256 * 2);
    unsigned short* w1T  = (unsigned short*)alloc((size_t)2048 * 256 * 2);
    unsigned short* w2T  = (unsigned short*)alloc((size_t)256 * 2048 * 2);
    float* bqv           = (float*)alloc(640 * 4);

    unsigned short* qout = (unsigned short*)alloc((size_t)MROWS * 384 * 2);  // 8.36 MB
    unsigned short* val  = (unsigned short*)alloc((size_t)MROWS * 256 * 2);
    unsigned short* attn = (unsigned short*)alloc((size_t)MROWS * 256 * 2);
    unsigned short* hb   = (unsigned short*)alloc((size_t)MROWS * 2048 * 2); // 44.6 MB
    unsigned short* xb16 = (unsigned short*)alloc((size_t)MROWS * 256 * 2);
    unsigned short* part = (unsigned short*)alloc((size_t)4 * MROWS * 256 * 2); // 22.3 MB

    // ---- weight prep (single launch) ----
    prep<<<1249, 256, 0, stream>>>(w_value, w_off, w_attn, w_out, w1, w2,
                                   b_value, b_off, b_attn, wqvT, woT, w1T, w2T, bqv);

    // ---- attention ----
    qv_gemm<<<425, 256, 0, stream>>>(src, pos, wqvT, bqv, val, qout);
    sampler<<<MROWS / 2, 256, 0, stream>>>(val, qout, attn);
    // x = LN(attn @ w_out + b_out + src) -> xb16   (fused, K=256)
    gemm_ln<<<340, 256, 0, stream>>>(attn, woT, b_out, src, g1, be1, xb16, 256);

    // ---- FFN ----
    ffn1_gemm<<<1360, 256, 0, stream>>>(xb16, w1T, b1, hb, 2048, 256, 256, 256);
    splitk_gemm<4><<<680, 256, 0, stream>>>(hb, w2T, part, 512, 2048, 2048);
    add_ln4<<<MROWS / 4, 256, 0, stream>>>(part, b2, xb16, g2, be2, out);
}

// Round 15
// 203.336 us; speedup vs baseline: 1.0468x; 1.0111x over previous
//
#include <hip/hip_runtime.h>
#include <math.h>

#define D 256
#define NH 8
#define NL 4
#define NP 4
#define DFF 2048
#define HD 32
#define BB 2
#define LEN 5440
#define MROWS (BB * LEN)   // 10880 = 85*128 = 340*32 = 2720*4

typedef __attribute__((ext_vector_type(8))) short short8;
typedef __attribute__((ext_vector_type(4))) float f32x4;
typedef unsigned int uint32;

__device__ __forceinline__ unsigned short f2bf(float f) {
    uint32 u = __float_as_uint(f);
    u += 0x7FFF + ((u >> 16) & 1);           // round-to-nearest-even
    return (unsigned short)(u >> 16);
}
__device__ __forceinline__ float bf2f(unsigned short h) {
    return __uint_as_float(((uint32)h) << 16);
}
__device__ __forceinline__ uint32 pack2(float a, float b) {
    return (uint32)f2bf(a) | ((uint32)f2bf(b) << 16);
}

// XCD-affinity swizzle: 85 row-tiles x ncols col-tiles.
__device__ __forceinline__ void swz85(int b, int ncols, int& row, int& col) {
    const int gsz = ncols << 3;
    const int full = 10 * gsz;
    if (b < full) {
        const int g = b / gsz, idx = b - g * gsz;
        row = (g << 3) + (idx & 7);
        col = idx >> 3;
    } else {
        const int idx = b - full;
        row = 80 + idx % 5;
        col = idx / 5;
    }
}

// ---------------------------------------------------------------------------
// prep: all weight transposes (fp32 [KxN] -> bf16 [NxK]) + bias concat.
// ---------------------------------------------------------------------------
__global__ void prep(const float* __restrict__ w_value, const float* __restrict__ w_off,
                     const float* __restrict__ w_attn, const float* __restrict__ w_out,
                     const float* __restrict__ w1, const float* __restrict__ w2,
                     const float* __restrict__ b_value, const float* __restrict__ b_off,
                     const float* __restrict__ b_attn,
                     unsigned short* __restrict__ wqvT, unsigned short* __restrict__ woT,
                     unsigned short* __restrict__ w1T, unsigned short* __restrict__ w2T,
                     float* __restrict__ bqv) {
    const int blk = blockIdx.x;
    if (blk >= 1248) {
        for (int i = threadIdx.x; i < 640; i += 256)
            bqv[i] = (i < 256) ? b_value[i] : (i < 512 ? b_off[i - 256] : b_attn[i - 512]);
        return;
    }
    const float* W; unsigned short* WT; int K, N, tid;
    if (blk < 64)       { W = w_value; WT = wqvT;             K = 256;  N = 256;  tid = blk; }
    else if (blk < 128) { W = w_off;   WT = wqvT + 256 * 256; K = 256;  N = 256;  tid = blk - 64; }
    else if (blk < 160) { W = w_attn;  WT = wqvT + 512 * 256; K = 256;  N = 128;  tid = blk - 128; }
    else if (blk < 224) { W = w_out;   WT = woT;              K = 256;  N = 256;  tid = blk - 160; }
    else if (blk < 736) { W = w1;      WT = w1T;              K = 256;  N = 2048; tid = blk - 224; }
    else                { W = w2;      WT = w2T;              K = 2048; N = 256;  tid = blk - 736; }
    const int ntx = N >> 5;
    const int nb = (tid % ntx) * 32, kb = (tid / ntx) * 32;

    __shared__ float tile[32][33];
    const int tx = threadIdx.x & 31, ty = threadIdx.x >> 5;
#pragma unroll
    for (int i = 0; i < 32; i += 8)
        tile[ty + i][tx] = W[(size_t)(kb + ty + i) * N + nb + tx];
    __syncthreads();
#pragma unroll
    for (int i = 0; i < 32; i += 8)
        WT[(size_t)(nb + ty + i) * K + kb + tx] = f2bf(tile[tx][ty + i]);
}

// ---------------------------------------------------------------------------
// ffn1 GEMM: C = relu(A @ BT^T + bias) -> bf16. 128x128 tile.
// LDS double-buffered K-loop: ONE barrier per K-step.
// ---------------------------------------------------------------------------
__global__ __launch_bounds__(256) void ffn1_gemm(
        const unsigned short* __restrict__ A,
        const unsigned short* __restrict__ BT, const float* __restrict__ bias,
        unsigned short* __restrict__ Cv, int N, int K, int lda, int ldb) {
    __shared__ unsigned short Ash[2][128][40];
    __shared__ unsigned short Bsh[2][128][40];

    int rowt, colt;
    swz85(blockIdx.x, N >> 7, rowt, colt);
    const int row0 = rowt * 128, col0 = colt * 128;

    const int t = threadIdx.x;
    const int wave = t >> 6, lane = t & 63;
    const int wr = wave >> 1, wc = wave & 1;
    const int lrow = lane & 15, quad = lane >> 4;
    const int srow = t >> 1;
    const int cb = (t & 1) * 16;

    const unsigned short* ap = A + (size_t)(row0 + srow) * lda + cb;
    const unsigned short* bp = BT + (size_t)(col0 + srow) * ldb + cb;

    f32x4 acc[4][4];
#pragma unroll
    for (int i = 0; i < 4; i++)
#pragma unroll
        for (int j = 0; j < 4; j++) acc[i][j] = (f32x4){0.f, 0.f, 0.f, 0.f};

    uint4 ra0 = *(const uint4*)(ap + 0), ra1 = *(const uint4*)(ap + 8);
    uint4 rb0 = *(const uint4*)(bp + 0), rb1 = *(const uint4*)(bp + 8);
    // tile 0 -> buf 0 (published by barrier at top of iter 0)
    *(uint4*)&Ash[0][srow][cb + 0] = ra0;
    *(uint4*)&Ash[0][srow][cb + 8] = ra1;
    *(uint4*)&Bsh[0][srow][cb + 0] = rb0;
    *(uint4*)&Bsh[0][srow][cb + 8] = rb1;
    if (32 < K) {
        ra0 = *(const uint4*)(ap + 32); ra1 = *(const uint4*)(ap + 40);
        rb0 = *(const uint4*)(bp + 32); rb1 = *(const uint4*)(bp + 40);
    }

    int i = 0;
    for (int kb = 0; kb < K; kb += 32, ++i) {
        __syncthreads();
        if (kb + 32 < K) {
            const int nb = (i + 1) & 1;
            *(uint4*)&Ash[nb][srow][cb + 0] = ra0;
            *(uint4*)&Ash[nb][srow][cb + 8] = ra1;
            *(uint4*)&Bsh[nb][srow][cb + 0] = rb0;
            *(uint4*)&Bsh[nb][srow][cb + 8] = rb1;
            if (kb + 64 < K) {
                ra0 = *(const uint4*)(ap + kb + 64 + 0);
                ra1 = *(const uint4*)(ap + kb + 64 + 8);
                rb0 = *(const uint4*)(bp + kb + 64 + 0);
                rb1 = *(const uint4*)(bp + kb + 64 + 8);
            }
        }
        const int cf = i & 1;
        short8 af[4], bfr[4];
#pragma unroll
        for (int mt = 0; mt < 4; mt++)
            af[mt] = *(const short8*)&Ash[cf][wr * 64 + mt * 16 + lrow][quad * 8];
#pragma unroll
        for (int nt = 0; nt < 4; nt++)
            bfr[nt] = *(const short8*)&Bsh[cf][wc * 64 + nt * 16 + lrow][quad * 8];
#pragma unroll
        for (int mt = 0; mt < 4; mt++)
#pragma unroll
            for (int nt = 0; nt < 4; nt++)
                acc[mt][nt] = __builtin_amdgcn_mfma_f32_16x16x32_bf16(
                    af[mt], bfr[nt], acc[mt][nt], 0, 0, 0);
    }

#pragma unroll
    for (int nt = 0; nt < 4; nt++) {
        const int col = col0 + wc * 64 + nt * 16 + lrow;
        const float bv = bias[col];
#pragma unroll
        for (int mt = 0; mt < 4; mt++) {
            f32x4 a = acc[mt][nt];
#pragma unroll
            for (int r = 0; r < 4; r++) {
                const int row = row0 + wr * 64 + mt * 16 + quad * 4 + r;
                Cv[(size_t)row * N + col] = f2bf(fmaxf(a[r] + bv, 0.f));
            }
        }
    }
}

// ---------------------------------------------------------------------------
// Split-K GEMM (N=256), bf16 partials. Double-buffered K-loop (1 barrier/step).
// ---------------------------------------------------------------------------
template <int NZ>
__global__ __launch_bounds__(256) void splitk_gemm(
        const unsigned short* __restrict__ A, const unsigned short* __restrict__ BT,
        unsigned short* __restrict__ part, int KC, int lda, int ldb) {
    __shared__ unsigned short Ash[2][128][40];
    __shared__ unsigned short Bsh[2][128][40];

    int rowt, cc;
    swz85(blockIdx.x, 2 * NZ, rowt, cc);
    const int row0 = rowt * 128;
    const int col0 = (cc & 1) * 128;
    const int z = cc >> 1;
    const int koff = z * KC;
    unsigned short* __restrict__ C = part + (size_t)z * MROWS * 256;

    const int t = threadIdx.x;
    const int wave = t >> 6, lane = t & 63;
    const int wr = wave >> 1, wc = wave & 1;
    const int lrow = lane & 15, quad = lane >> 4;
    const int srow = t >> 1;
    const int cb = (t & 1) * 16;

    const unsigned short* ap = A + (size_t)(row0 + srow) * lda + koff + cb;
    const unsigned short* bp = BT + (size_t)(col0 + srow) * ldb + koff + cb;

    f32x4 acc[4][4];
#pragma unroll
    for (int i = 0; i < 4; i++)
#pragma unroll
        for (int j = 0; j < 4; j++) acc[i][j] = (f32x4){0.f, 0.f, 0.f, 0.f};

    uint4 ra0 = *(const uint4*)(ap + 0), ra1 = *(const uint4*)(ap + 8);
    uint4 rb0 = *(const uint4*)(bp + 0), rb1 = *(const uint4*)(bp + 8);
    *(uint4*)&Ash[0][srow][cb + 0] = ra0;
    *(uint4*)&Ash[0][srow][cb + 8] = ra1;
    *(uint4*)&Bsh[0][srow][cb + 0] = rb0;
    *(uint4*)&Bsh[0][srow][cb + 8] = rb1;
    if (32 < KC) {
        ra0 = *(const uint4*)(ap + 32); ra1 = *(const uint4*)(ap + 40);
        rb0 = *(const uint4*)(bp + 32); rb1 = *(const uint4*)(bp + 40);
    }

    int i = 0;
    for (int kb = 0; kb < KC; kb += 32, ++i) {
        __syncthreads();
        if (kb + 32 < KC) {
            const int nb = (i + 1) & 1;
            *(uint4*)&Ash[nb][srow][cb + 0] = ra0;
            *(uint4*)&Ash[nb][srow][cb + 8] = ra1;
            *(uint4*)&Bsh[nb][srow][cb + 0] = rb0;
            *(uint4*)&Bsh[nb][srow][cb + 8] = rb1;
            if (kb + 64 < KC) {
                ra0 = *(const uint4*)(ap + kb + 64 + 0);
                ra1 = *(const uint4*)(ap + kb + 64 + 8);
                rb0 = *(const uint4*)(bp + kb + 64 + 0);
                rb1 = *(const uint4*)(bp + kb + 64 + 8);
            }
        }
        const int cf = i & 1;
        short8 af[4], bfr[4];
#pragma unroll
        for (int mt = 0; mt < 4; mt++)
            af[mt] = *(const short8*)&Ash[cf][wr * 64 + mt * 16 + lrow][quad * 8];
#pragma unroll
        for (int nt = 0; nt < 4; nt++)
            bfr[nt] = *(const short8*)&Bsh[cf][wc * 64 + nt * 16 + lrow][quad * 8];
#pragma unroll
        for (int mt = 0; mt < 4; mt++)
#pragma unroll
            for (int nt = 0; nt < 4; nt++)
                acc[mt][nt] = __builtin_amdgcn_mfma_f32_16x16x32_bf16(
                    af[mt], bfr[nt], acc[mt][nt], 0, 0, 0);
    }

#pragma unroll
    for (int nt = 0; nt < 4; nt++) {
        const int col = col0 + wc * 64 + nt * 16 + lrow;
#pragma unroll
        for (int mt = 0; mt < 4; mt++) {
            f32x4 a = acc[mt][nt];
#pragma unroll
            for (int r = 0; r < 4; r++) {
                const int row = row0 + wr * 64 + mt * 16 + quad * 4 + r;
                C[(size_t)row * 256 + col] = f2bf(a[r]);
            }
        }
    }
}

// ---------------------------------------------------------------------------
// Fused GEMM + bias + residual + LayerNorm (K=256 proj). Output: bf16 only.
// ---------------------------------------------------------------------------
__global__ __launch_bounds__(256) void gemm_ln(
        const unsigned short* __restrict__ A, const unsigned short* __restrict__ BT,
        const float* __restrict__ bias, const float* __restrict__ rsd,
        const float* __restrict__ g, const float* __restrict__ be,
        unsigned short* __restrict__ out16, int K) {
    __shared__ __align__(16) unsigned short Ash[32][40];
    __shared__ __align__(16) unsigned short Bsh[256][40];
    __shared__ float red1[4][32], red2[4][32];

    const int row0 = blockIdx.x * 32;
    const int t = threadIdx.x;
    const int wave = t >> 6, lane = t & 63;
    const int lrow = lane & 15, quad = lane >> 4;

    const int ar = t >> 3, ac = (t & 7) * 4;
    const unsigned short* ap = A + (size_t)(row0 + ar) * K + ac;
    const int br = t >> 1, cb = (t & 1) * 16;
    const unsigned short* bp0 = BT + (size_t)br * K + cb;
    const unsigned short* bp1 = BT + (size_t)(128 + br) * K + cb;

    f32x4 acc[2][4];
#pragma unroll
    for (int i = 0; i < 2; i++)
#pragma unroll
        for (int j = 0; j < 4; j++) acc[i][j] = (f32x4){0.f, 0.f, 0.f, 0.f};

    uint2 ra = *(const uint2*)ap;
    uint4 rb00 = *(const uint4*)(bp0 + 0), rb01 = *(const uint4*)(bp0 + 8);
    uint4 rb10 = *(const uint4*)(bp1 + 0), rb11 = *(const uint4*)(bp1 + 8);

    for (int kb = 0; kb < K; kb += 32) {
        __syncthreads();
        *(uint2*)&Ash[ar][ac] = ra;
        *(uint4*)&Bsh[br][cb + 0] = rb00;
        *(uint4*)&Bsh[br][cb + 8] = rb01;
        *(uint4*)&Bsh[128 + br][cb + 0] = rb10;
        *(uint4*)&Bsh[128 + br][cb + 8] = rb11;
        __syncthreads();
        if (kb + 32 < K) {
            ra   = *(const uint2*)(ap + kb + 32);
            rb00 = *(const uint4*)(bp0 + kb + 32 + 0);
            rb01 = *(const uint4*)(bp0 + kb + 32 + 8);
            rb10 = *(const uint4*)(bp1 + kb + 32 + 0);
            rb11 = *(const uint4*)(bp1 + kb + 32 + 8);
        }

        short8 af[2], bfr[4];
#pragma unroll
        for (int mt = 0; mt < 2; mt++)
            af[mt] = *(const short8*)&Ash[mt * 16 + lrow][quad * 8];
#pragma unroll
        for (int nt = 0; nt < 4; nt++)
            bfr[nt] = *(const short8*)&Bsh[wave * 64 + nt * 16 + lrow][quad * 8];
#pragma unroll
        for (int mt = 0; mt < 2; mt++)
#pragma unroll
            for (int nt = 0; nt < 4; nt++)
                acc[mt][nt] = __builtin_amdgcn_mfma_f32_16x16x32_bf16(
                    af[mt], bfr[nt], acc[mt][nt], 0, 0, 0);
    }

    float gv[4], bev[4], bv[4];
#pragma unroll
    for (int nt = 0; nt < 4; nt++) {
        const int col = wave * 64 + nt * 16 + lrow;
        bv[nt] = bias[col];
        gv[nt] = g[col];
        bev[nt] = be[col];
    }

    float v[2][4][4];
#pragma unroll
    for (int mt = 0; mt < 2; mt++)
#pragma unroll
        for (int r = 0; r < 4; r++) {
            const int row = row0 + mt * 16 + quad * 4 + r;
#pragma unroll
            for (int nt = 0; nt < 4; nt++) {
                const int col = wave * 64 + nt * 16 + lrow;
                v[mt][nt][r] = acc[mt][nt][r] + bv[nt] + rsd[(size_t)row * 256 + col];
            }
        }

#pragma unroll
    for (int mt = 0; mt < 2; mt++)
#pragma unroll
        for (int r = 0; r < 4; r++) {
            float s1 = v[mt][0][r] + v[mt][1][r] + v[mt][2][r] + v[mt][3][r];
            float s2 = v[mt][0][r] * v[mt][0][r] + v[mt][1][r] * v[mt][1][r] +
                       v[mt][2][r] * v[mt][2][r] + v[mt][3][r] * v[mt][3][r];
#pragma unroll
            for (int o = 1; o < 16; o <<= 1) {
                s1 += __shfl_xor(s1, o, 16);
                s2 += __shfl_xor(s2, o, 16);
            }
            if (lrow == 0) {
                const int rr = mt * 16 + quad * 4 + r;
                red1[wave][rr] = s1;
                red2[wave][rr] = s2;
            }
        }
    __syncthreads();

#pragma unroll
    for (int mt = 0; mt < 2; mt++)
#pragma unroll
        for (int r = 0; r < 4; r++) {
            const int rr = mt * 16 + quad * 4 + r;
            const float su = red1[0][rr] + red1[1][rr] + red1[2][rr] + red1[3][rr];
            const float sq = red2[0][rr] + red2[1][rr] + red2[2][rr] + red2[3][rr];
            const float mean = su * (1.0f / 256.0f);
            const float var = fmaxf(sq * (1.0f / 256.0f) - mean * mean, 0.f);
            const float rstd = rsqrtf(var + 1e-5f);
            const size_t rowoff = (size_t)(row0 + rr) * 256;
#pragma unroll
            for (int nt = 0; nt < 4; nt++) {
                const int col = wave * 64 + nt * 16 + lrow;
                const float o = (v[mt][nt][r] - mean) * rstd * gv[nt] + bev[nt];
                out16[rowoff + col] = f2bf(o);
            }
        }
}

// ---------------------------------------------------------------------------
// Merged value+query GEMM: flat grid 425, swizzled. Double-buffered K-loop.
// col < 256 -> val (bf16); col >= 256 -> qout16 (bf16, stride 384).
// ---------------------------------------------------------------------------
__global__ __launch_bounds__(256) void qv_gemm(
        const float* __restrict__ src, const float* __restrict__ pos,
        const unsigned short* __restrict__ BT, const float* __restrict__ bias,
        unsigned short* __restrict__ val, unsigned short* __restrict__ qout16) {
    __shared__ unsigned short Ash[2][128][40];
    __shared__ unsigned short Bsh[2][128][40];

    int rowt, colt;
    swz85(blockIdx.x, 5, rowt, colt);
    const int row0 = rowt * 128, col0 = colt * 128;
    const bool addp = (col0 >= 256);

    const int t = threadIdx.x;
    const int wave = t >> 6, lane = t & 63;
    const int wr = wave >> 1, wc = wave & 1;
    const int lrow = lane & 15, quad = lane >> 4;
    const int srow = t >> 1;
    const int cb = (t & 1) * 16;

    const float* ap = src + (size_t)(row0 + srow) * 256 + cb;
    const float* pp = pos + (size_t)(row0 + srow) * 256 + cb;
    const unsigned short* bp = BT + (size_t)(col0 + srow) * 256 + cb;

    f32x4 acc[4][4];
#pragma unroll
    for (int i = 0; i < 4; i++)
#pragma unroll
        for (int j = 0; j < 4; j++) acc[i][j] = (f32x4){0.f, 0.f, 0.f, 0.f};

    float4 fa[4]; float4 fp[4]; uint4 rb0, rb1;
    auto packA = [&](int buf) {
        float4 f0 = fa[0], f1 = fa[1], f2 = fa[2], f3 = fa[3];
        if (addp) {
            f0.x += fp[0].x; f0.y += fp[0].y; f0.z += fp[0].z; f0.w += fp[0].w;
            f1.x += fp[1].x; f1.y += fp[1].y; f1.z += fp[1].z; f1.w += fp[1].w;
            f2.x += fp[2].x; f2.y += fp[2].y; f2.z += fp[2].z; f2.w += fp[2].w;
            f3.x += fp[3].x; f3.y += fp[3].y; f3.z += fp[3].z; f3.w += fp[3].w;
        }
        uint4 u0 = make_uint4(pack2(f0.x, f0.y), pack2(f0.z, f0.w),
                              pack2(f1.x, f1.y), pack2(f1.z, f1.w));
        uint4 u1 = make_uint4(pack2(f2.x, f2.y), pack2(f2.z, f2.w),
                              pack2(f3.x, f3.y), pack2(f3.z, f3.w));
        *(uint4*)&Ash[buf][srow][cb + 0] = u0;
        *(uint4*)&Ash[buf][srow][cb + 8] = u1;
        *(uint4*)&Bsh[buf][srow][cb + 0] = rb0;
        *(uint4*)&Bsh[buf][srow][cb + 8] = rb1;
    };
    auto loadA = [&](int kb) {
#pragma unroll
        for (int j = 0; j < 4; j++) fa[j] = *(const float4*)(ap + kb + 4 * j);
        if (addp) {
#pragma unroll
            for (int j = 0; j < 4; j++) fp[j] = *(const float4*)(pp + kb + 4 * j);
        }
        rb0 = *(const uint4*)(bp + kb + 0);
        rb1 = *(const uint4*)(bp + kb + 8);
    };

    loadA(0);
    packA(0);
    loadA(32);

    int i = 0;
    for (int kb = 0; kb < 256; kb += 32, ++i) {
        __syncthreads();
        if (kb + 32 < 256) {
            packA((i + 1) & 1);
            if (kb + 64 < 256) loadA(kb + 64);
        }
        const int cf = i & 1;
        short8 af[4], bfr[4];
#pragma unroll
        for (int mt = 0; mt < 4; mt++)
            af[mt] = *(const short8*)&Ash[cf][wr * 64 + mt * 16 + lrow][quad * 8];
#pragma unroll
        for (int nt = 0; nt < 4; nt++)
            bfr[nt] = *(const short8*)&Bsh[cf][wc * 64 + nt * 16 + lrow][quad * 8];
#pragma unroll
        for (int mt = 0; mt < 4; mt++)
#pragma unroll
            for (int nt = 0; nt < 4; nt++)
                acc[mt][nt] = __builtin_amdgcn_mfma_f32_16x16x32_bf16(
                    af[mt], bfr[nt], acc[mt][nt], 0, 0, 0);
    }

#pragma unroll
    for (int nt = 0; nt < 4; nt++) {
        const int col = col0 + wc * 64 + nt * 16 + lrow;
        const float bv = bias[col];
#pragma unroll
        for (int mt = 0; mt < 4; mt++) {
            f32x4 a = acc[mt][nt];
#pragma unroll
            for (int r = 0; r < 4; r++) {
                const int row = row0 + wr * 64 + mt * 16 + quad * 4 + r;
                float v = a[r] + bv;
                if (col < 256)
                    val[(size_t)row * 256 + col] = f2bf(v);
                else
                    qout16[(size_t)row * 384 + (col - 256)] = f2bf(v);
            }
        }
    }
}

// ---------------------------------------------------------------------------
// Two-phase sampler, 2 queries per block, ushort2 gathers; qout in bf16.
// ---------------------------------------------------------------------------
__global__ void sampler(const unsigned short* __restrict__ val,
                        const unsigned short* __restrict__ qout16,
                        unsigned short* __restrict__ out) {
    __shared__ __align__(16) int   sIdx[2][128][4];
    __shared__ __align__(16) float sW[2][128][4];
    const int t = threadIdx.x;
    const int sub = t >> 7;
    const int tt = t & 127;
    const int bq = blockIdx.x * 2 + sub;
    const int b = bq / LEN, q = bq % LEN;

    {
        const int h = tt >> 4, p = tt & 15;
        const int l = p >> 2;

        float refx, refy;
        if (q < 4096) {
            int rq = q >> 6, cq = q & 63;
            refx = (cq + 0.5f) * (1.0f / 64.0f);
            refy = (rq + 0.5f) * (1.0f / 64.0f);
        } else if (q < 5120) {
            int qq = q - 4096;
            int rq = qq >> 5, cq = qq & 31;
            refx = (cq + 0.5f) * (1.0f / 32.0f);
            refy = (rq + 0.5f) * (1.0f / 32.0f);
        } else if (q < 5376) {
            int qq = q - 5120;
            int rq = qq >> 4, cq = qq & 15;
            refx = (cq + 0.5f) * (1.0f / 16.0f);
            refy = (rq + 0.5f) * (1.0f / 16.0f);
        } else {
            int qq = q - 5376;
            int rq = qq >> 3, cq = qq & 7;
            refx = (cq + 0.5f) * (1.0f / 8.0f);
            refy = (rq + 0.5f) * (1.0f / 8.0f);
        }

        float lv = bf2f(qout16[(size_t)bq * 384 + 256 + tt]);
        float mx = lv;
#pragma unroll
        for (int o = 1; o < 16; o <<= 1) mx = fmaxf(mx, __shfl_xor(mx, o, 16));
        float e = expf(lv - mx);
        float s = e;
#pragma unroll
        for (int o = 1; o < 16; o <<= 1) s += __shfl_xor(s, o, 16);
        const float aw = e / s;

        const uint32 opair = *(const uint32*)&qout16[(size_t)bq * 384 + h * 32 + p * 2];
        const float ox = bf2f((unsigned short)opair);
        const float oy = bf2f((unsigned short)(opair >> 16));

        const int LST[4] = {0, 4096, 5120, 5376};
        const int WW = 64 >> l;
        const float rw = 1.0f / (float)WW;

        float x = (refx + ox * rw) * (float)WW - 0.5f;
        float y = (refy + oy * rw) * (float)WW - 0.5f;
        float x0f = floorf(x), y0f = floorf(y);
        float dx = x - x0f, dy = y - y0f;
        int x0 = (int)x0f, y0 = (int)y0f;

        const int base = (b * LEN + LST[l]) * 256 + h * 32;
        int xs[2] = {x0, x0 + 1}, ys[2] = {y0, y0 + 1};
        float wx[2] = {1.f - dx, dx}, wy[2] = {1.f - dy, dy};
        int ic[4]; float wc4[4];
#pragma unroll
        for (int cy = 0; cy < 2; cy++)
#pragma unroll
            for (int cx = 0; cx < 2; cx++) {
                int xi = xs[cx], yi = ys[cy];
                bool vld = (xi >= 0) && (xi < WW) && (yi >= 0) && (yi < WW);
                int xc = min(max(xi, 0), WW - 1);
                int yc = min(max(yi, 0), WW - 1);
                ic[cy * 2 + cx] = base + (yc * WW + xc) * 256;
                wc4[cy * 2 + cx] = vld ? wx[cx] * wy[cy] * aw : 0.f;
            }
        *(int4*)&sIdx[sub][tt][0] = make_int4(ic[0], ic[1], ic[2], ic[3]);
        *(float4*)&sW[sub][tt][0] = make_float4(wc4[0], wc4[1], wc4[2], wc4[3]);
    }
    __syncthreads();

    const int h = tt >> 4, dp = tt & 15;
    const unsigned short* vald = val + 2 * dp;
    float acc0 = 0.f, acc1 = 0.f;
#pragma unroll 4
    for (int p = 0; p < 16; p++) {
        const int r = h * 16 + p;
        int4 iv = *(const int4*)&sIdx[sub][r][0];
        float4 wv = *(const float4*)&sW[sub][r][0];
        uint32 u0 = *(const uint32*)(vald + iv.x);
        uint32 u1 = *(const uint32*)(vald + iv.y);
        uint32 u2 = *(const uint32*)(vald + iv.z);
        uint32 u3 = *(const uint32*)(vald + iv.w);
        acc0 += bf2f((unsigned short)u0) * wv.x + bf2f((unsigned short)u1) * wv.y +
                bf2f((unsigned short)u2) * wv.z + bf2f((unsigned short)u3) * wv.w;
        acc1 += bf2f((unsigned short)(u0 >> 16)) * wv.x + bf2f((unsigned short)(u1 >> 16)) * wv.y +
                bf2f((unsigned short)(u2 >> 16)) * wv.z + bf2f((unsigned short)(u3 >> 16)) * wv.w;
    }
    *(uint32*)&out[(size_t)bq * D + h * HD + 2 * dp] = pack2(acc0, acc1);
}

// ---------------------------------------------------------------------------
// Final LN, wave-per-row (no __syncthreads): out = LN(sum_z part16[z] + bias
// + rsd16) * g + be. Grid = M/4, block 256 = 4 waves = 4 rows.
// ---------------------------------------------------------------------------
__global__ void add_ln4(const unsigned short* __restrict__ part16,
                        const float* __restrict__ bias,
                        const unsigned short* __restrict__ rsd16,
                        const float* __restrict__ g, const float* __restrict__ be,
                        float* __restrict__ out) {
    const int wave = threadIdx.x >> 6, lane = threadIdx.x & 63;
    const int row = blockIdx.x * 4 + wave;
    const int c0 = lane * 4;
    const size_t i = (size_t)row * 256 + c0;

    float v[4];
    {
        ushort4 r = *(const ushort4*)&rsd16[i];
        float4 bv = *(const float4*)&bias[c0];
        v[0] = bf2f(r.x) + bv.x; v[1] = bf2f(r.y) + bv.y;
        v[2] = bf2f(r.z) + bv.z; v[3] = bf2f(r.w) + bv.w;
    }
#pragma unroll
    for (int z = 0; z < 4; z++) {
        ushort4 p = *(const ushort4*)&part16[(size_t)z * MROWS * 256 + i];
        v[0] += bf2f(p.x); v[1] += bf2f(p.y); v[2] += bf2f(p.z); v[3] += bf2f(p.w);
    }
    float s1 = v[0] + v[1] + v[2] + v[3];
    float s2 = v[0] * v[0] + v[1] * v[1] + v[2] * v[2] + v[3] * v[3];
#pragma unroll
    for (int o = 32; o > 0; o >>= 1) {
        s1 += __shfl_xor(s1, o, 64);
        s2 += __shfl_xor(s2, o, 64);
    }
    const float mean = s1 * (1.0f / 256.0f);
    const float var = fmaxf(s2 * (1.0f / 256.0f) - mean * mean, 0.f);
    const float rstd = rsqrtf(var + 1e-5f);

    float4 gv = *(const float4*)&g[c0];
    float4 bev = *(const float4*)&be[c0];
    float4 o4;
    o4.x = (v[0] - mean) * rstd * gv.x + bev.x;
    o4.y = (v[1] - mean) * rstd * gv.y + bev.y;
    o4.z = (v[2] - mean) * rstd * gv.z + bev.z;
    o4.w = (v[3] - mean) * rstd * gv.w + bev.w;
    *(float4*)&out[i] = o4;
}

// ---------------------------------------------------------------------------
extern "C" void kernel_launch(void* const* d_in, const int* in_sizes, int n_in,
                              void* d_out, int out_size, void* d_ws, size_t ws_size,
                              hipStream_t stream) {
    const float* src     = (const float*)d_in[0];
    const float* pos     = (const float*)d_in[1];
    const float* w_value = (const float*)d_in[4];
    const float* b_value = (const float*)d_in[5];
    const float* w_off   = (const float*)d_in[6];
    const float* b_off   = (const float*)d_in[7];
    const float* w_attn  = (const float*)d_in[8];
    const float* b_attn  = (const float*)d_in[9];
    const float* w_out   = (const float*)d_in[10];
    const float* b_out   = (const float*)d_in[11];
    const float* w1      = (const float*)d_in[12];
    const float* b1      = (const float*)d_in[13];
    const float* w2      = (const float*)d_in[14];
    const float* b2      = (const float*)d_in[15];
    const float* g1      = (const float*)d_in[16];
    const float* be1     = (const float*)d_in[17];
    const float* g2      = (const float*)d_in[18];
    const float* be2     = (const float*)d_in[19];
    float* out = (float*)d_out;

    // ---- workspace layout (~95 MB of the 256 MiB ws) ----
    size_t off = 0;
    auto alloc = [&](size_t bytes) -> char* {
        char* p = (char*)d_ws + off;
        off += (bytes + 255) & ~(size_t)255;
        return p;
    };
    unsigned short* wqvT = (unsigned short*)alloc((size_t)640 * 256 * 2);
    unsigned short* woT  = (unsigned short*)alloc(256 * 256 * 2);
    unsigned short* w1T  = (unsigned short*)alloc((size_t)2048 * 256 * 2);
    unsigned short* w2T  = (unsigned short*)alloc((size_t)256 * 2048 * 2);
    float* bqv           = (float*)alloc(640 * 4);

    unsigned short* qout = (unsigned short*)alloc((size_t)MROWS * 384 * 2);  // 8.36 MB
    unsigned short* val  = (unsigned short*)alloc((size_t)MROWS * 256 * 2);
    unsigned short* attn = (unsigned short*)alloc((size_t)MROWS * 256 * 2);
    unsigned short* hb   = (unsigned short*)alloc((size_t)MROWS * 2048 * 2); // 44.6 MB
    unsigned short* xb16 = (unsigned short*)alloc((size_t)MROWS * 256 * 2);
    unsigned short* part = (unsigned short*)alloc((size_t)4 * MROWS * 256 * 2); // 22.3 MB

    // ---- weight prep (single launch) ----
    prep<<<1249, 256, 0, stream>>>(w_value, w_off, w_attn, w_out, w1, w2,
                                   b_value, b_off, b_attn, wqvT, woT, w1T, w2T, bqv);

    // ---- attention ----
    qv_gemm<<<425, 256, 0, stream>>>(src, pos, wqvT, bqv, val, qout);
    sampler<<<MROWS / 2, 256, 0, stream>>>(val, qout, attn);
    // x = LN(attn @ w_out + b_out + src) -> xb16   (fused, K=256)
    gemm_ln<<<340, 256, 0, stream>>>(attn, woT, b_out, src, g1, be1, xb16, 256);

    // ---- FFN ----
    ffn1_gemm<<<1360, 256, 0, stream>>>(xb16, w1T, b1, hb, 2048, 256, 256, 256);
    splitk_gemm<4><<<680, 256, 0, stream>>>(hb, w2T, part, 512, 2048, 2048);
    add_ln4<<<MROWS / 4, 256, 0, stream>>>(part, b2, xb16, g2, be2, out);
}